// Round 14
// baseline (94.498 us; speedup 1.0000x reference)
//
#include <hip/hip_runtime.h>
#include <hip/hip_bf16.h>

#define NUM_GT 25
#define NUM_PRED 40
#define GRID 2048
#define BLOCK 256
#define ROWS 64

// ws layout (u32 words):
//   [r*65 + s], r=0..63 : partial SAD sums; sbin s: 0..24 = g_gt(s),
//                         25..64 = g_pr(s-25)
//   [WS_OV + p], p=0..40 : overlap bitmask row p
#define WS_OV    (ROWS * 65)
#define WS_WORDS (WS_OV + 41)

#if defined(__has_builtin)
#  if __has_builtin(__builtin_amdgcn_sad_u8)
#    define SAD(A, W, K) (A) = __builtin_amdgcn_sad_u8((W), (K), (A))
#  endif
#endif
#ifndef SAD
#  define SAD(A, W, K) asm("v_sad_u8 %0, %1, %2, %0" : "+v"(A) : "v"(W), "s"(K))
#endif

__device__ __forceinline__ unsigned packg(int4 g) {
    return (unsigned)g.x | ((unsigned)g.y << 8) |
           ((unsigned)g.z << 16) | ((unsigned)g.w << 24);
}
__device__ __forceinline__ unsigned packp(float4 p) {
    return (unsigned)p.x | ((unsigned)p.y << 8) |
           ((unsigned)p.z << 16) | ((unsigned)p.w << 24);
}

template <int NB>
__device__ __forceinline__ void reduce_flush(
    unsigned* acc, int sbin0, int lane, unsigned* __restrict__ ws, int row)
{
    #pragma unroll
    for (int j = 0; j < NB; ++j) {
        unsigned c = acc[j];
        c += __shfl_down(c, 32, 64);
        c += __shfl_down(c, 16, 64);
        c += __shfl_down(c, 8, 64);
        c += __shfl_down(c, 4, 64);
        c += __shfl_down(c, 2, 64);
        c += __shfl_down(c, 1, 64);
        if (lane == 0 && c) atomicAdd(&ws[row * 65 + sbin0 + j], c);
    }
}

// gt-wave: NB gt bins starting at KB0, plus overlap ds_or for 8 of the 16
// voxels per group (words WSEL, WSEL+1). Own private sovl table -> no
// barrier, no cross-wave races; fire-and-forget ds_or (R12: hides fully).
template <int NB, int KB0, int WSEL>
__device__ __forceinline__ void scan_gt_or(
    const float4* __restrict__ p4, const int4* __restrict__ g4,
    int n16, int i0, int S, int lane,
    unsigned* __restrict__ ws, int row, unsigned* sovl_w)
{
    sovl_w[lane] = 0u;                       // wave-private init

    unsigned acc[NB];
    #pragma unroll
    for (int j = 0; j < NB; ++j) acc[j] = 0u;

    for (int i = i0; i < n16; i += S) {
        const int q = i * 4;
        int4 g0 = g4[q], g1 = g4[q + 1], g2 = g4[q + 2], g3 = g4[q + 3];
        float4 pw0 = p4[q + WSEL], pw1 = p4[q + WSEL + 1];

        const int4 gm0 = (WSEL == 0) ? g0 : g2;
        const int4 gm1 = (WSEL == 0) ? g1 : g3;
        atomicOr(&sovl_w[(unsigned)pw0.x & 63], 1u << ((unsigned)gm0.x & 31));
        atomicOr(&sovl_w[(unsigned)pw0.y & 63], 1u << ((unsigned)gm0.y & 31));
        atomicOr(&sovl_w[(unsigned)pw0.z & 63], 1u << ((unsigned)gm0.z & 31));
        atomicOr(&sovl_w[(unsigned)pw0.w & 63], 1u << ((unsigned)gm0.w & 31));
        atomicOr(&sovl_w[(unsigned)pw1.x & 63], 1u << ((unsigned)gm1.x & 31));
        atomicOr(&sovl_w[(unsigned)pw1.y & 63], 1u << ((unsigned)gm1.y & 31));
        atomicOr(&sovl_w[(unsigned)pw1.z & 63], 1u << ((unsigned)gm1.z & 31));
        atomicOr(&sovl_w[(unsigned)pw1.w & 63], 1u << ((unsigned)gm1.w & 31));

        unsigned W0 = packg(g0), W1 = packg(g1), W2 = packg(g2), W3 = packg(g3);
        #pragma unroll
        for (int b = 0; b < NB; ++b) {
            const unsigned K = (unsigned)((KB0 + b) * 0x01010101u);
            SAD(acc[b], W0, K); SAD(acc[b], W1, K);
            SAD(acc[b], W2, K); SAD(acc[b], W3, K);
        }
    }
    reduce_flush<NB>(acc, KB0, lane, ws, row);

    if (lane < 41) {
        unsigned v = sovl_w[lane];
        if (v) atomicOr(&ws[WS_OV + lane], v);
    }
}

// pred-wave: NB pred bins starting at KB0; pure load+SAD.
template <int NB, int KB0>
__device__ __forceinline__ void scan_pr(
    const float4* __restrict__ p4, int n16, int i0, int S, int lane,
    unsigned* __restrict__ ws, int row)
{
    unsigned acc[NB];
    #pragma unroll
    for (int j = 0; j < NB; ++j) acc[j] = 0u;

    for (int i = i0; i < n16; i += S) {
        const int q = i * 4;
        float4 w0 = p4[q], w1 = p4[q + 1], w2 = p4[q + 2], w3 = p4[q + 3];
        unsigned W0 = packp(w0), W1 = packp(w1), W2 = packp(w2), W3 = packp(w3);
        #pragma unroll
        for (int b = 0; b < NB; ++b) {
            const unsigned K = (unsigned)((KB0 + b) * 0x01010101u);
            SAD(acc[b], W0, K); SAD(acc[b], W1, K);
            SAD(acc[b], W2, K); SAD(acc[b], W3, K);
        }
    }
    reduce_flush<NB>(acc, 25 + KB0, lane, ws, row);
}

// ---------------------------------------------------------------------------
// Histogram, ovl_kernel-shaped (R13: same traffic at 3x the speed): bins
// split across the 4 waves (13/12 gt + overlap, 20/20 pred), <=20 clean VGPR
// accumulators per wave, ~60-100 VALU between 4-8-load batches, no barriers,
// grid 2048 = 8 blocks/CU. Same-block waves sweep the same addresses, so the
// duplicate array sweeps hit L1/L2 (FETCH stays ~one-pass).
// ---------------------------------------------------------------------------
__global__ __launch_bounds__(BLOCK, 6) void hist_kernel(
    const float* __restrict__ pred, const int* __restrict__ gt,
    unsigned* __restrict__ ws, int n)
{
    __shared__ unsigned sovl[2][64];         // wave-private overlap tables

    const int tid  = threadIdx.x;
    const int lane = tid & 63;
    const int wave = tid >> 6;

    const int n16 = n >> 4;                  // 16-voxel groups
    const int S   = GRID * 64;               // lanes per wave-type
    const int i0  = blockIdx.x * 64 + lane;
    const int row = blockIdx.x & (ROWS - 1);
    const float4* __restrict__ p4 = (const float4*)pred;
    const int4* __restrict__  g4 = (const int4*)gt;

    if      (wave == 0) scan_gt_or<13, 0, 0>(p4, g4, n16, i0, S, lane, ws, row, sovl[0]);
    else if (wave == 1) scan_gt_or<12, 13, 2>(p4, g4, n16, i0, S, lane, ws, row, sovl[1]);
    else if (wave == 2) scan_pr<20, 0>(p4, n16, i0, S, lane, ws, row);
    else                scan_pr<20, 20>(p4, n16, i0, S, lane, ws, row);

    // defensive scalar tail for n % 16 (none for 256^3)
    if (blockIdx.x == 0 && tid == 0) {
        for (int v = n16 << 4; v < n; ++v) {
            int p = (int)pred[v];
            int g = gt[v];
            for (int b = 0; b < 25; ++b) atomicAdd(&ws[b], (unsigned)abs(g - b));
            for (int b = 0; b < 40; ++b) atomicAdd(&ws[25 + b], (unsigned)abs(p - b));
            atomicOr(&ws[WS_OV + min(max(p, 0), NUM_PRED)], 1u << (g & 31));
        }
    }
}

// ---------------------------------------------------------------------------
// Finisher: sum 64 partial rows, exact second-difference counts (int64) +
// fp64 dice (proven absmax = 0, rounds 6-13).
// ---------------------------------------------------------------------------
__global__ __launch_bounds__(128) void finish_kernel(
    const unsigned* __restrict__ ws, float* __restrict__ out, int n)
{
    __shared__ long long gsum[65];
    __shared__ long long psz[41];
    __shared__ unsigned ovs[41];
    const int t = threadIdx.x;

    if (t < 65) {
        unsigned s = 0;
        for (int r = 0; r < ROWS; ++r) s += ws[r * 65 + t];
        gsum[t] = (long long)s;
    }
    if (t < 41) ovs[t] = ws[WS_OV + t];
    __syncthreads();

    const long long N = n;
    if (t < 41) {                            // pred_sizes[P], P = t
        const long long Sp = gsum[25];
        int P = t;
        long long f;
        if (P == 0)       f = (N - gsum[25 + 0] + gsum[25 + 1]) / 2;
        else if (P <= 38) f = (gsum[25 + P - 1] - 2 * gsum[25 + P] + gsum[25 + P + 1]) / 2;
        else if (P == 39) f = (gsum[25 + 38] - 2 * gsum[25 + 39] + (40 * N - Sp)) / 2;
        else              f = (gsum[25 + 39] - 39 * N + Sp) / 2;   // P = 40
        psz[P] = f;
    }
    __syncthreads();

    if (t < 64) {
        const int lane = t;
        const long long Sg = gsum[0];
        double dice = 0.0;
        int present = 0;
        if (lane < 25) {                     // gt component label L = lane+1
            int L = lane + 1;
            long long gs;
            if (L <= 23)      gs = (gsum[L - 1] - 2 * gsum[L] + gsum[L + 1]) / 2;
            else if (L == 24) gs = (gsum[23] - 2 * gsum[24] + (25 * N - Sg)) / 2;
            else              gs = (gsum[24] - 24 * N + Sg) / 2;   // L = 25
            if (gs > 0) {
                present = 1;
                double un = 0.0;
                const unsigned bit = 1u << L;
                for (int p = 0; p < 41; ++p)
                    if (ovs[p] & bit) un += (double)psz[p];
                dice = 2.0 * (double)gs / (un + (double)gs + 1.0);
            }
        }
        int fp = 0;
        if (lane < 41) {
            if (psz[lane] > 0 && (ovs[lane] & 0x3FFFFFEu) == 0) fp = 1;
        }

        int num_gt = __popcll(__ballot(present != 0));
        int nfp    = __popcll(__ballot(fp != 0));
        #pragma unroll
        for (int o = 32; o >= 1; o >>= 1) dice += __shfl_xor(dice, o, 64);

        if (lane == 0) out[0] = (float)(dice / (double)(num_gt + nfp));
    }
}

extern "C" void kernel_launch(void* const* d_in, const int* in_sizes, int n_in,
                              void* d_out, int out_size, void* d_ws, size_t ws_size,
                              hipStream_t stream) {
    const float* pred = (const float*)d_in[0];
    const int* gt = (const int*)d_in[1];
    float* out = (float*)d_out;
    unsigned* ws = (unsigned*)d_ws;
    const int n = in_sizes[0];

    hipMemsetAsync(ws, 0, WS_WORDS * sizeof(unsigned), stream);

    hist_kernel<<<GRID, BLOCK, 0, stream>>>(pred, gt, ws, n);
    finish_kernel<<<1, 128, 0, stream>>>(ws, out, n);
}

// Round 15
// 63.218 us; speedup vs baseline: 1.4948x; 1.4948x over previous
//
#include <hip/hip_runtime.h>
#include <hip/hip_bf16.h>

#define NUM_GT 25
#define NUM_PRED 40
#define GRID 2048
#define BLOCK 256
#define ROWS 64

// ws layout (u32 words):
//   [r*65 + s], r=0..63 : partial SAD sums; sbin s: 0..24 = g_gt(s),
//                         25..64 = g_pr(s-25)
//   [WS_OV + p], p=0..40 : overlap bitmask row p
#define WS_OV    (ROWS * 65)
#define WS_WORDS (WS_OV + 41)

#if defined(__has_builtin)
#  if __has_builtin(__builtin_amdgcn_sad_u8)
#    define SAD(A, W, K) (A) = __builtin_amdgcn_sad_u8((W), (K), (A))
#  endif
#endif
#ifndef SAD
#  define SAD(A, W, K) asm("v_sad_u8 %0, %1, %2, %0" : "+v"(A) : "v"(W), "s"(K))
#endif

__device__ __forceinline__ unsigned packg(int4 g) {
    return (unsigned)g.x | ((unsigned)g.y << 8) |
           ((unsigned)g.z << 16) | ((unsigned)g.w << 24);
}
__device__ __forceinline__ unsigned packp(float4 p) {
    return (unsigned)p.x | ((unsigned)p.y << 8) |
           ((unsigned)p.z << 16) | ((unsigned)p.w << 24);
}

template <int NB>
__device__ __forceinline__ void reduce_flush(
    unsigned* acc, int sbin0, int lane, unsigned* __restrict__ ws, int row)
{
    #pragma unroll
    for (int j = 0; j < NB; ++j) {
        unsigned c = acc[j];
        c += __shfl_down(c, 32, 64);
        c += __shfl_down(c, 16, 64);
        c += __shfl_down(c, 8, 64);
        c += __shfl_down(c, 4, 64);
        c += __shfl_down(c, 2, 64);
        c += __shfl_down(c, 1, 64);
        if (lane == 0 && c) atomicAdd(&ws[row * 65 + sbin0 + j], c);
    }
}

// wave 0: gt bins 0..12 + overlap ds_or for all 16 voxels (reads gt+pred).
__device__ __forceinline__ void role0(
    const float4* __restrict__ p4, const int4* __restrict__ g4,
    int nch, int lane, unsigned* __restrict__ ws, int row, unsigned* sovl)
{
    sovl[lane] = 0u;                         // wave-private, no barrier needed

    unsigned acc[13];
    #pragma unroll
    for (int j = 0; j < 13; ++j) acc[j] = 0u;

    for (int c = blockIdx.x; c < nch; c += GRID) {
        const int q = c * 256 + lane * 4;    // float4 index
        int4  g0 = g4[q], g1 = g4[q+1], g2 = g4[q+2], g3 = g4[q+3];
        float4 pq0 = p4[q], pq1 = p4[q+1], pq2 = p4[q+2], pq3 = p4[q+3];

        // fire-and-forget overlap bits (R12: fully absorbed)
        atomicOr(&sovl[(unsigned)pq0.x & 63], 1u << ((unsigned)g0.x & 31));
        atomicOr(&sovl[(unsigned)pq0.y & 63], 1u << ((unsigned)g0.y & 31));
        atomicOr(&sovl[(unsigned)pq0.z & 63], 1u << ((unsigned)g0.z & 31));
        atomicOr(&sovl[(unsigned)pq0.w & 63], 1u << ((unsigned)g0.w & 31));
        atomicOr(&sovl[(unsigned)pq1.x & 63], 1u << ((unsigned)g1.x & 31));
        atomicOr(&sovl[(unsigned)pq1.y & 63], 1u << ((unsigned)g1.y & 31));
        atomicOr(&sovl[(unsigned)pq1.z & 63], 1u << ((unsigned)g1.z & 31));
        atomicOr(&sovl[(unsigned)pq1.w & 63], 1u << ((unsigned)g1.w & 31));
        atomicOr(&sovl[(unsigned)pq2.x & 63], 1u << ((unsigned)g2.x & 31));
        atomicOr(&sovl[(unsigned)pq2.y & 63], 1u << ((unsigned)g2.y & 31));
        atomicOr(&sovl[(unsigned)pq2.z & 63], 1u << ((unsigned)g2.z & 31));
        atomicOr(&sovl[(unsigned)pq2.w & 63], 1u << ((unsigned)g2.w & 31));
        atomicOr(&sovl[(unsigned)pq3.x & 63], 1u << ((unsigned)g3.x & 31));
        atomicOr(&sovl[(unsigned)pq3.y & 63], 1u << ((unsigned)g3.y & 31));
        atomicOr(&sovl[(unsigned)pq3.z & 63], 1u << ((unsigned)g3.z & 31));
        atomicOr(&sovl[(unsigned)pq3.w & 63], 1u << ((unsigned)g3.w & 31));

        unsigned W0 = packg(g0), W1 = packg(g1), W2 = packg(g2), W3 = packg(g3);
        #pragma unroll
        for (int b = 0; b < 13; ++b) {
            const unsigned K = (unsigned)(b * 0x01010101u);
            SAD(acc[b], W0, K); SAD(acc[b], W1, K);
            SAD(acc[b], W2, K); SAD(acc[b], W3, K);
        }
    }
    reduce_flush<13>(acc, 0, lane, ws, row);

    if (lane < 41) {
        unsigned v = sovl[lane];
        if (v) atomicOr(&ws[WS_OV + lane], v);
    }
}

// wave 1: gt bins 13..24 (gt only).
__device__ __forceinline__ void role1(
    const int4* __restrict__ g4, int nch, int lane,
    unsigned* __restrict__ ws, int row)
{
    unsigned acc[12];
    #pragma unroll
    for (int j = 0; j < 12; ++j) acc[j] = 0u;

    for (int c = blockIdx.x; c < nch; c += GRID) {
        const int q = c * 256 + lane * 4;
        int4 g0 = g4[q], g1 = g4[q+1], g2 = g4[q+2], g3 = g4[q+3];
        unsigned W0 = packg(g0), W1 = packg(g1), W2 = packg(g2), W3 = packg(g3);
        #pragma unroll
        for (int b = 0; b < 12; ++b) {
            const unsigned K = (unsigned)((13 + b) * 0x01010101u);
            SAD(acc[b], W0, K); SAD(acc[b], W1, K);
            SAD(acc[b], W2, K); SAD(acc[b], W3, K);
        }
    }
    reduce_flush<12>(acc, 13, lane, ws, row);
}

// waves 2/3: 20 pred bins each (pred only).
template <int KB0>
__device__ __forceinline__ void role_pr(
    const float4* __restrict__ p4, int nch, int lane,
    unsigned* __restrict__ ws, int row)
{
    unsigned acc[20];
    #pragma unroll
    for (int j = 0; j < 20; ++j) acc[j] = 0u;

    for (int c = blockIdx.x; c < nch; c += GRID) {
        const int q = c * 256 + lane * 4;
        float4 w0 = p4[q], w1 = p4[q+1], w2 = p4[q+2], w3 = p4[q+3];
        unsigned W0 = packp(w0), W1 = packp(w1), W2 = packp(w2), W3 = packp(w3);
        #pragma unroll
        for (int b = 0; b < 20; ++b) {
            const unsigned K = (unsigned)((KB0 + b) * 0x01010101u);
            SAD(acc[b], W0, K); SAD(acc[b], W1, K);
            SAD(acc[b], W2, K); SAD(acc[b], W3, K);
        }
    }
    reduce_flush<20>(acc, 25 + KB0, lane, ws, row);
}

// ---------------------------------------------------------------------------
// Histogram: R12's hot-loop shape (16 vox/lane/iter, loads up front, fused
// fire-and-forget ds_or, no barriers) with the 65 bins SPLIT across the
// block's 4 waves (13/12/20/20, <=20 accums -> ~50 arch VGPRs -> 32 waves/CU
// possible). All waves of a block sweep the SAME 1024-voxel window per
// iteration (gt read by waves 0-1, pred by 0,2,3) so L1 serves duplicates.
// ---------------------------------------------------------------------------
__global__ __launch_bounds__(BLOCK) void hist_kernel(
    const float* __restrict__ pred, const int* __restrict__ gt,
    unsigned* __restrict__ ws, int n)
{
    __shared__ unsigned sovl[64];            // wave0-private

    const int tid  = threadIdx.x;
    const int lane = tid & 63;
    const int wave = tid >> 6;

    const int nch = n >> 10;                 // 1024-voxel windows
    const int row = blockIdx.x & (ROWS - 1);
    const float4* __restrict__ p4 = (const float4*)pred;
    const int4* __restrict__  g4 = (const int4*)gt;

    if      (wave == 0) role0(p4, g4, nch, lane, ws, row, sovl);
    else if (wave == 1) role1(g4, nch, lane, ws, row);
    else if (wave == 2) role_pr<0>(p4, nch, lane, ws, row);
    else                role_pr<20>(p4, nch, lane, ws, row);

    // defensive scalar tail for n % 1024 (none for 256^3)
    if (blockIdx.x == 0 && tid == 0) {
        for (int v = nch << 10; v < n; ++v) {
            int p = (int)pred[v];
            int g = gt[v];
            for (int b = 0; b < 25; ++b) atomicAdd(&ws[b], (unsigned)abs(g - b));
            for (int b = 0; b < 40; ++b) atomicAdd(&ws[25 + b], (unsigned)abs(p - b));
            atomicOr(&ws[WS_OV + min(max(p, 0), NUM_PRED)], 1u << (g & 31));
        }
    }
}

// ---------------------------------------------------------------------------
// Finisher: sum 64 partial rows, exact second-difference counts (int64) +
// fp64 dice (proven absmax = 0, rounds 6-14).
// ---------------------------------------------------------------------------
__global__ __launch_bounds__(128) void finish_kernel(
    const unsigned* __restrict__ ws, float* __restrict__ out, int n)
{
    __shared__ long long gsum[65];
    __shared__ long long psz[41];
    __shared__ unsigned ovs[41];
    const int t = threadIdx.x;

    if (t < 65) {
        unsigned s = 0;
        for (int r = 0; r < ROWS; ++r) s += ws[r * 65 + t];
        gsum[t] = (long long)s;
    }
    if (t < 41) ovs[t] = ws[WS_OV + t];
    __syncthreads();

    const long long N = n;
    if (t < 41) {                            // pred_sizes[P], P = t
        const long long Sp = gsum[25];
        int P = t;
        long long f;
        if (P == 0)       f = (N - gsum[25 + 0] + gsum[25 + 1]) / 2;
        else if (P <= 38) f = (gsum[25 + P - 1] - 2 * gsum[25 + P] + gsum[25 + P + 1]) / 2;
        else if (P == 39) f = (gsum[25 + 38] - 2 * gsum[25 + 39] + (40 * N - Sp)) / 2;
        else              f = (gsum[25 + 39] - 39 * N + Sp) / 2;   // P = 40
        psz[P] = f;
    }
    __syncthreads();

    if (t < 64) {
        const int lane = t;
        const long long Sg = gsum[0];
        double dice = 0.0;
        int present = 0;
        if (lane < 25) {                     // gt component label L = lane+1
            int L = lane + 1;
            long long gs;
            if (L <= 23)      gs = (gsum[L - 1] - 2 * gsum[L] + gsum[L + 1]) / 2;
            else if (L == 24) gs = (gsum[23] - 2 * gsum[24] + (25 * N - Sg)) / 2;
            else              gs = (gsum[24] - 24 * N + Sg) / 2;   // L = 25
            if (gs > 0) {
                present = 1;
                double un = 0.0;
                const unsigned bit = 1u << L;
                for (int p = 0; p < 41; ++p)
                    if (ovs[p] & bit) un += (double)psz[p];
                dice = 2.0 * (double)gs / (un + (double)gs + 1.0);
            }
        }
        int fp = 0;
        if (lane < 41) {
            if (psz[lane] > 0 && (ovs[lane] & 0x3FFFFFEu) == 0) fp = 1;
        }

        int num_gt = __popcll(__ballot(present != 0));
        int nfp    = __popcll(__ballot(fp != 0));
        #pragma unroll
        for (int o = 32; o >= 1; o >>= 1) dice += __shfl_xor(dice, o, 64);

        if (lane == 0) out[0] = (float)(dice / (double)(num_gt + nfp));
    }
}

extern "C" void kernel_launch(void* const* d_in, const int* in_sizes, int n_in,
                              void* d_out, int out_size, void* d_ws, size_t ws_size,
                              hipStream_t stream) {
    const float* pred = (const float*)d_in[0];
    const int* gt = (const int*)d_in[1];
    float* out = (float*)d_out;
    unsigned* ws = (unsigned*)d_ws;
    const int n = in_sizes[0];

    hipMemsetAsync(ws, 0, WS_WORDS * sizeof(unsigned), stream);

    hist_kernel<<<GRID, BLOCK, 0, stream>>>(pred, gt, ws, n);
    finish_kernel<<<1, 128, 0, stream>>>(ws, out, n);
}

// Round 16
// 55.862 us; speedup vs baseline: 1.6916x; 1.1317x over previous
//
#include <hip/hip_runtime.h>
#include <hip/hip_bf16.h>

#define NUM_GT 25
#define NUM_PRED 40
#define PAD 32         // 128 B between global words

// ws u32 word offsets (each on its own 128B line):
//   GT_W(b), b=0..24 : g_gt(b) = sum |gt - b|     (SAD accumulators)
//   PR_W(p), p=0..39 : g_pr(p) = sum |pred - p|
//   OV_W(p), p=0..40 : overlap bitmask row p
#define GT_W(b)  ((b) * PAD)
#define PR_W(p)  ((25 + (p)) * PAD)
#define OV_W(p)  ((65 + (p)) * PAD)
#define WS_WORDS (106 * PAD)

#define GRID 1536      // 6 blocks/CU x 256 CUs, exactly resident (no tail)
#define BLOCK 256

#if defined(__has_builtin)
#  if __has_builtin(__builtin_amdgcn_sad_u8)
#    define SAD(A, W, K) (A) = __builtin_amdgcn_sad_u8((W), (K), (A))
#  endif
#endif
#ifndef SAD
#  define SAD(A, W, K) asm("v_sad_u8 %0, %1, %2, %0" : "+v"(A) : "v"(W), "s"(K))
#endif

__device__ __forceinline__ unsigned packg(int4 g) {
    return (unsigned)g.x | ((unsigned)g.y << 8) |
           ((unsigned)g.z << 16) | ((unsigned)g.w << 24);
}
__device__ __forceinline__ unsigned packp(float4 p) {
    return (unsigned)p.x | ((unsigned)p.y << 8) |
           ((unsigned)p.z << 16) | ((unsigned)p.w << 24);
}

// pair-packed u16 shfl tree -> LDS shist (proven R6-R12 epilogue, generalized).
// Per-lane acc <= 48 vox * 63 = 3024; after 2 shfl levels <= 12096; 4-wave
// stash sum <= 48384 < 65536 (u16-safe throughout).
template <int NPAIR>
__device__ __forceinline__ void tree_flush(
    const unsigned* acc, int sbin0, int tid, int lane, int wave,
    unsigned (*stash)[16][34], unsigned* shist)
{
    #pragma unroll
    for (int jp = 0; jp < NPAIR; ++jp) {
        unsigned v = acc[2 * jp] | (acc[2 * jp + 1] << 16);
        v += __shfl_down(v, 32, 64);
        v += __shfl_down(v, 16, 64);
        if (lane < 16) stash[wave][lane][jp] = v;
    }
    __syncthreads();
    for (int i = tid; i < NPAIR * 16; i += BLOCK) {
        int jp = i >> 4, sl = i & 15;
        unsigned a = stash[0][sl][jp] + stash[1][sl][jp]
                   + stash[2][sl][jp] + stash[3][sl][jp];
        unsigned lo = a & 0xFFFFu, hi = a >> 16;
        lo += __shfl_down(lo, 8, 16);  hi += __shfl_down(hi, 8, 16);
        lo += __shfl_down(lo, 4, 16);  hi += __shfl_down(hi, 4, 16);
        lo += __shfl_down(lo, 2, 16);  hi += __shfl_down(hi, 2, 16);
        lo += __shfl_down(lo, 1, 16);  hi += __shfl_down(hi, 1, 16);
        if (sl == 0) {
            if (lo) atomicAdd(&shist[sbin0 + 2 * jp], lo);
            if (hi) atomicAdd(&shist[sbin0 + 2 * jp + 1], hi);
        }
    }
    __syncthreads();
}

// ---------------------------------------------------------------------------
// Two-pass full-bins SAD histogram (R12 dataflow at HIGH occupancy):
//   pass 1: gt bins 0..24 + pred bins 0..7 (33 accums) + fused ds_or,
//           8 vox/lane/iter (4 loads, both arrays).
//   pass 2: pred bins 8..39 (32 accums), 16 vox/lane/iter (4 loads, pred
//           only, L2/L3-warm re-read of the same addresses).
// Peak live accums 33+loads ~ 65 regs -> 6 waves/SIMD (vs 2.5 at 66 accums).
// ---------------------------------------------------------------------------
__global__ __launch_bounds__(BLOCK, 6) void hist_kernel(
    const float* __restrict__ pred, const int* __restrict__ gt,
    unsigned* __restrict__ ws, int n)
{
    __shared__ unsigned sovl[64];
    __shared__ unsigned shist[66];
    __shared__ unsigned stash[4][16][34];

    const int tid  = threadIdx.x;
    const int lane = tid & 63;
    const int wave = tid >> 6;

    if (tid < 64) sovl[tid] = 0u;
    if (tid < 66) shist[tid] = 0u;
    __syncthreads();

    const int stride = GRID * BLOCK;
    const int gtid   = blockIdx.x * BLOCK + tid;
    const float4* __restrict__ p4 = (const float4*)pred;
    const int4* __restrict__  g4 = (const int4*)gt;

    // ================= pass 1: gt 0..24 + pred 0..7 + overlap =============
    {
        unsigned acc[34];                    // [33] = dummy pad for the tree
        #pragma unroll
        for (int j = 0; j < 34; ++j) acc[j] = 0u;

        const int n8 = n >> 3;               // 8-voxel groups
        for (int i = gtid; i < n8; i += stride) {
            const int q = i * 2;
            int4  g0 = g4[q], g1 = g4[q + 1];
            float4 pq0 = p4[q], pq1 = p4[q + 1];

            atomicOr(&sovl[(unsigned)pq0.x & 63], 1u << ((unsigned)g0.x & 31));
            atomicOr(&sovl[(unsigned)pq0.y & 63], 1u << ((unsigned)g0.y & 31));
            atomicOr(&sovl[(unsigned)pq0.z & 63], 1u << ((unsigned)g0.z & 31));
            atomicOr(&sovl[(unsigned)pq0.w & 63], 1u << ((unsigned)g0.w & 31));
            atomicOr(&sovl[(unsigned)pq1.x & 63], 1u << ((unsigned)g1.x & 31));
            atomicOr(&sovl[(unsigned)pq1.y & 63], 1u << ((unsigned)g1.y & 31));
            atomicOr(&sovl[(unsigned)pq1.z & 63], 1u << ((unsigned)g1.z & 31));
            atomicOr(&sovl[(unsigned)pq1.w & 63], 1u << ((unsigned)g1.w & 31));

            unsigned G0 = packg(g0), G1 = packg(g1);
            unsigned P0 = packp(pq0), P1 = packp(pq1);
            #pragma unroll
            for (int b = 0; b < 25; ++b) {
                const unsigned K = (unsigned)(b * 0x01010101u);
                SAD(acc[b], G0, K); SAD(acc[b], G1, K);
            }
            #pragma unroll
            for (int b = 0; b < 8; ++b) {
                const unsigned K = (unsigned)(b * 0x01010101u);
                SAD(acc[25 + b], P0, K); SAD(acc[25 + b], P1, K);
            }
        }
        tree_flush<17>(acc, 0, tid, lane, wave, stash, shist);
    }

    // ================= pass 2: pred 8..39 (pred only, cache-warm) =========
    {
        unsigned acc[32];
        #pragma unroll
        for (int j = 0; j < 32; ++j) acc[j] = 0u;

        const int n16 = n >> 4;              // 16-voxel groups
        for (int i = gtid; i < n16; i += stride) {
            const int q = i * 4;
            float4 w0 = p4[q], w1 = p4[q + 1], w2 = p4[q + 2], w3 = p4[q + 3];
            unsigned W0 = packp(w0), W1 = packp(w1);
            unsigned W2 = packp(w2), W3 = packp(w3);
            #pragma unroll
            for (int b = 0; b < 32; ++b) {
                const unsigned K = (unsigned)((8 + b) * 0x01010101u);
                SAD(acc[b], W0, K); SAD(acc[b], W1, K);
                SAD(acc[b], W2, K); SAD(acc[b], W3, K);
            }
        }
        tree_flush<16>(acc, 33, tid, lane, wave, stash, shist);
    }

    // defensive scalar tails (empty for n = 256^3)
    if (blockIdx.x == 0 && tid == 0) {
        for (int v = (n >> 3) << 3; v < n; ++v) {   // pass-1 coverage
            int p = (int)pred[v];
            int g = gt[v];
            for (int b = 0; b < 25; ++b) atomicAdd(&ws[GT_W(b)], (unsigned)abs(g - b));
            for (int b = 0; b < 8; ++b)  atomicAdd(&ws[PR_W(b)], (unsigned)abs(p - b));
            atomicOr(&ws[OV_W(min(max(p, 0), NUM_PRED))], 1u << (g & 31));
        }
        for (int v = (n >> 4) << 4; v < n; ++v) {   // pass-2 coverage
            int p = (int)pred[v];
            for (int b = 8; b < 40; ++b) atomicAdd(&ws[PR_W(b)], (unsigned)abs(p - b));
        }
    }

    // ---- per-block -> global (65 + 41 atomics, 128B-padded) ----
    for (int i = tid; i < 65; i += BLOCK) {
        unsigned s = shist[i];
        if (s) atomicAdd(&ws[i * PAD], s);
    }
    if (tid < 41) {
        unsigned v = sovl[tid];
        if (v) atomicOr(&ws[OV_W(tid)], v);
    }
}

// ---------------------------------------------------------------------------
// Finisher: second-difference count extraction (exact int64) + fp64 dice
// (proven absmax = 0, rounds 6-15).
// ---------------------------------------------------------------------------
__global__ __launch_bounds__(64) void finish_kernel(
    const unsigned* __restrict__ ws, float* __restrict__ out, int n)
{
    __shared__ long long gg[25], gp[40], psz[41];
    __shared__ unsigned ov[41];
    const int lane = threadIdx.x;
    if (lane < 25) gg[lane] = (long long)ws[GT_W(lane)];
    if (lane < 40) gp[lane] = (long long)ws[PR_W(lane)];
    if (lane < 41) ov[lane] = ws[OV_W(lane)];
    __syncthreads();

    const long long N = n, Sg = gg[0], Sp = gp[0];

    if (lane < 41) {                         // pred_sizes[P], P = lane
        int P = lane;
        long long f;
        if (P == 0)       f = (N - gp[0] + gp[1]) / 2;
        else if (P <= 38) f = (gp[P - 1] - 2 * gp[P] + gp[P + 1]) / 2;
        else if (P == 39) f = (gp[38] - 2 * gp[39] + (40 * N - Sp)) / 2;
        else              f = (gp[39] - 39 * N + Sp) / 2;   // P = 40
        psz[P] = f;
    }
    __syncthreads();

    double dice = 0.0;
    int present = 0;
    if (lane < 25) {                         // gt component label L = lane+1
        int L = lane + 1;
        long long gs;
        if (L <= 23)      gs = (gg[L - 1] - 2 * gg[L] + gg[L + 1]) / 2;
        else if (L == 24) gs = (gg[23] - 2 * gg[24] + (25 * N - Sg)) / 2;
        else              gs = (gg[24] - 24 * N + Sg) / 2;  // L = 25
        if (gs > 0) {
            present = 1;
            double un = 0.0;
            const unsigned bit = 1u << L;
            for (int p = 0; p < 41; ++p)
                if (ov[p] & bit) un += (double)psz[p];
            dice = 2.0 * (double)gs / (un + (double)gs + 1.0);
        }
    }
    int fp = 0;
    if (lane < 41) {
        if (psz[lane] > 0 && (ov[lane] & 0x3FFFFFEu) == 0) fp = 1;
    }

    int num_gt = __popcll(__ballot(present != 0));
    int nfp    = __popcll(__ballot(fp != 0));
    #pragma unroll
    for (int o = 32; o >= 1; o >>= 1) dice += __shfl_xor(dice, o, 64);

    if (lane == 0) out[0] = (float)(dice / (double)(num_gt + nfp));
}

extern "C" void kernel_launch(void* const* d_in, const int* in_sizes, int n_in,
                              void* d_out, int out_size, void* d_ws, size_t ws_size,
                              hipStream_t stream) {
    const float* pred = (const float*)d_in[0];
    const int* gt = (const int*)d_in[1];
    float* out = (float*)d_out;
    unsigned* ws = (unsigned*)d_ws;
    const int n = in_sizes[0];

    hipMemsetAsync(ws, 0, WS_WORDS * sizeof(unsigned), stream);

    hist_kernel<<<GRID, BLOCK, 0, stream>>>(pred, gt, ws, n);
    finish_kernel<<<1, 64, 0, stream>>>(ws, out, n);
}

// Round 17
// 45.210 us; speedup vs baseline: 2.0902x; 1.2356x over previous
//
#include <hip/hip_runtime.h>
#include <hip/hip_bf16.h>

#define NUM_GT 25
#define NUM_PRED 40
#define PAD 32         // 128 B between global words

// ws u32 word offsets (each on its own 128B line):
//   GT_W(b), b=0..24 : g_gt(b) = sum |gt - b|     (SAD accumulators)
//   PR_W(p), p=0..39 : g_pr(p) = sum |pred - p|
//   OV_W(p), p=0..40 : overlap bitmask row p
#define GT_W(b)  ((b) * PAD)
#define PR_W(p)  ((25 + (p)) * PAD)
#define OV_W(p)  ((65 + (p)) * PAD)
#define WS_WORDS (106 * PAD)

#define GRID  1024
#define BLOCK 256
#define TILE  2048     // voxels per block-tile (8 KB per array)

#if defined(__has_builtin)
#  if __has_builtin(__builtin_amdgcn_sad_u8)
#    define SAD(A, W, K) (A) = __builtin_amdgcn_sad_u8((W), (K), (A))
#  endif
#endif
#ifndef SAD
#  define SAD(A, W, K) asm("v_sad_u8 %0, %1, %2, %0" : "+v"(A) : "v"(W), "s"(K))
#endif

#define AS1 __attribute__((address_space(1)))
#define AS3 __attribute__((address_space(3)))

// Stage one wave's quarter of a tile array: 512 u32 = 2 async 1KB writes.
// LDS dest is wave-uniform base (+ lane*16 by HW); global src is per-lane.
// Zero VGPRs held by in-flight data -> no AGPR-pressure interaction.
__device__ __forceinline__ void stage_tile(
    const unsigned* __restrict__ gsrc, unsigned* ldst, int wid, int lane)
{
#if defined(__has_builtin) && __has_builtin(__builtin_amdgcn_global_load_lds)
    const unsigned* s0 = gsrc + wid * 512 + lane * 4;
    unsigned* d0 = ldst + wid * 512;
    __builtin_amdgcn_global_load_lds((const AS1 unsigned*)s0,
                                     (AS3 unsigned*)d0, 16, 0, 0);
    __builtin_amdgcn_global_load_lds((const AS1 unsigned*)(s0 + 256),
                                     (AS3 unsigned*)(d0 + 256), 16, 0, 0);
#else
    *(uint4*)(ldst + wid * 512 + lane * 4) =
        *(const uint4*)(gsrc + wid * 512 + lane * 4);
    *(uint4*)(ldst + wid * 512 + 256 + lane * 4) =
        *(const uint4*)(gsrc + wid * 512 + 256 + lane * 4);
#endif
}

// ---------------------------------------------------------------------------
// Convoy-breaking SAD histogram: global_load_lds double buffer. Per iter:
// issue async stage of tile t+1 (vmcnt drains at the barrier AFTER compute,
// so HBM streams during the SAD block), ds_read_b128 + pack + 130 SADs +
// fire-and-forget ds_or on tile t. 8 iters, exact fit for n = 256^3.
// ---------------------------------------------------------------------------
__global__ __launch_bounds__(BLOCK) void hist_kernel(
    const float* __restrict__ pred, const int* __restrict__ gt,
    unsigned* __restrict__ ws, int n)
{
    __shared__ unsigned lgt[2][TILE];        // 16 KB (raw i32 labels)
    __shared__ unsigned lpr[2][TILE];        // 16 KB (raw f32 bits)
    __shared__ unsigned sovl[64];
    __shared__ unsigned shist[66];

    const int tid  = threadIdx.x;
    const int lane = tid & 63;
    const int wid  = tid >> 6;

    if (tid < 64) sovl[tid] = 0u;
    if (tid < 66) shist[tid] = 0u;

    // acc[0..24]=g_gt(0..24); acc[25..64]=g_pr(0..39); acc[65] dummy pad
    unsigned acc[66];
    #pragma unroll
    for (int j = 0; j < 66; ++j) acc[j] = 0u;

    const unsigned* __restrict__ gu = (const unsigned*)gt;
    const unsigned* __restrict__ pu = (const unsigned*)pred;
    const int ntiles = n / TILE;

    int t = blockIdx.x;
    int cur = 0;
    if (t < ntiles) {
        stage_tile(gu + (size_t)t * TILE, &lgt[0][0], wid, lane);
        stage_tile(pu + (size_t)t * TILE, &lpr[0][0], wid, lane);
    }
    __syncthreads();                         // drains prologue stage

    for (; t < ntiles; t += GRID) {
        const int tn = t + GRID;
        if (tn < ntiles) {                   // issue NEXT tile (async)
            stage_tile(gu + (size_t)tn * TILE, &lgt[cur ^ 1][0], wid, lane);
            stage_tile(pu + (size_t)tn * TILE, &lpr[cur ^ 1][0], wid, lane);
        }

        // ---- compute current tile from LDS ----
        const uint4* g4 = (const uint4*)(&lgt[cur][0] + wid * 512);
        const uint4* p4 = (const uint4*)(&lpr[cur][0] + wid * 512);
        #pragma unroll
        for (int h = 0; h < 2; ++h) {
            uint4 gw = g4[h * 64 + lane];
            uint4 pw = p4[h * 64 + lane];
            unsigned b0 = (unsigned)__uint_as_float(pw.x);
            unsigned b1 = (unsigned)__uint_as_float(pw.y);
            unsigned b2 = (unsigned)__uint_as_float(pw.z);
            unsigned b3 = (unsigned)__uint_as_float(pw.w);

            atomicOr(&sovl[b0 & 63], 1u << (gw.x & 31));
            atomicOr(&sovl[b1 & 63], 1u << (gw.y & 31));
            atomicOr(&sovl[b2 & 63], 1u << (gw.z & 31));
            atomicOr(&sovl[b3 & 63], 1u << (gw.w & 31));

            unsigned G = gw.x | (gw.y << 8) | (gw.z << 16) | (gw.w << 24);
            unsigned P = b0 | (b1 << 8) | (b2 << 16) | (b3 << 24);
            #pragma unroll
            for (int b = 0; b < 25; ++b) {
                const unsigned K = (unsigned)(b * 0x01010101u);
                SAD(acc[b], G, K);
            }
            #pragma unroll
            for (int b = 0; b < 40; ++b) {
                const unsigned K = (unsigned)(b * 0x01010101u);
                SAD(acc[25 + b], P, K);
            }
        }

        __syncthreads();     // vmcnt drain lands HERE (after compute)
        cur ^= 1;
    }

    // defensive scalar tail (empty for 256^3)
    if (blockIdx.x == 0 && tid == 0) {
        for (int v = ntiles * TILE; v < n; ++v) {
            int p = (int)pred[v];
            int g = gt[v];
            for (int b = 0; b < 25; ++b) atomicAdd(&ws[GT_W(b)], (unsigned)abs(g - b));
            for (int b = 0; b < 40; ++b) atomicAdd(&ws[PR_W(b)], (unsigned)abs(p - b));
            atomicOr(&ws[OV_W(min(max(p, 0), NUM_PRED))], 1u << (g & 31));
        }
    }

    // ---- epilogue: pair-packed u16 tree; stash overlaid on dead lgt buffer
    // (per-lane acc <= 64 vox * 40 = 2560; halves <= 40960, u16-safe)
    unsigned (*stash)[16][34] = (unsigned(*)[16][34])(&lgt[0][0]);
    #pragma unroll
    for (int jp = 0; jp < 33; ++jp) {
        unsigned v = acc[2 * jp] | (acc[2 * jp + 1] << 16);
        v += __shfl_down(v, 32, 64);
        v += __shfl_down(v, 16, 64);
        if (lane < 16) stash[wid][lane][jp] = v;
    }
    __syncthreads();

    for (int i = tid; i < 33 * 16; i += BLOCK) {
        int jp = i >> 4, sl = i & 15;
        unsigned a = stash[0][sl][jp] + stash[1][sl][jp]
                   + stash[2][sl][jp] + stash[3][sl][jp];
        unsigned lo = a & 0xFFFFu, hi = a >> 16;
        lo += __shfl_down(lo, 8, 16);  hi += __shfl_down(hi, 8, 16);
        lo += __shfl_down(lo, 4, 16);  hi += __shfl_down(hi, 4, 16);
        lo += __shfl_down(lo, 2, 16);  hi += __shfl_down(hi, 2, 16);
        lo += __shfl_down(lo, 1, 16);  hi += __shfl_down(hi, 1, 16);
        if (sl == 0) {
            if (lo) atomicAdd(&shist[2 * jp], lo);
            if (hi && 2 * jp + 1 < 65) atomicAdd(&shist[2 * jp + 1], hi);
        }
    }
    __syncthreads();

    for (int i = tid; i < 65; i += BLOCK) {
        unsigned s = shist[i];
        if (s) atomicAdd(&ws[i * PAD], s);
    }
    if (tid < 41) {
        unsigned v = sovl[tid];
        if (v) atomicOr(&ws[OV_W(tid)], v);
    }
}

// ---------------------------------------------------------------------------
// Finisher: second-difference count extraction (exact int64) + fp64 dice
// (proven absmax = 0, rounds 6-16).
// ---------------------------------------------------------------------------
__global__ __launch_bounds__(64) void finish_kernel(
    const unsigned* __restrict__ ws, float* __restrict__ out, int n)
{
    __shared__ long long gg[25], gp[40], psz[41];
    __shared__ unsigned ov[41];
    const int lane = threadIdx.x;
    if (lane < 25) gg[lane] = (long long)ws[GT_W(lane)];
    if (lane < 40) gp[lane] = (long long)ws[PR_W(lane)];
    if (lane < 41) ov[lane] = ws[OV_W(lane)];
    __syncthreads();

    const long long N = n, Sg = gg[0], Sp = gp[0];

    if (lane < 41) {                         // pred_sizes[P], P = lane
        int P = lane;
        long long f;
        if (P == 0)       f = (N - gp[0] + gp[1]) / 2;
        else if (P <= 38) f = (gp[P - 1] - 2 * gp[P] + gp[P + 1]) / 2;
        else if (P == 39) f = (gp[38] - 2 * gp[39] + (40 * N - Sp)) / 2;
        else              f = (gp[39] - 39 * N + Sp) / 2;   // P = 40
        psz[P] = f;
    }
    __syncthreads();

    double dice = 0.0;
    int present = 0;
    if (lane < 25) {                         // gt component label L = lane+1
        int L = lane + 1;
        long long gs;
        if (L <= 23)      gs = (gg[L - 1] - 2 * gg[L] + gg[L + 1]) / 2;
        else if (L == 24) gs = (gg[23] - 2 * gg[24] + (25 * N - Sg)) / 2;
        else              gs = (gg[24] - 24 * N + Sg) / 2;  // L = 25
        if (gs > 0) {
            present = 1;
            double un = 0.0;
            const unsigned bit = 1u << L;
            for (int p = 0; p < 41; ++p)
                if (ov[p] & bit) un += (double)psz[p];
            dice = 2.0 * (double)gs / (un + (double)gs + 1.0);
        }
    }
    int fp = 0;
    if (lane < 41) {
        if (psz[lane] > 0 && (ov[lane] & 0x3FFFFFEu) == 0) fp = 1;
    }

    int num_gt = __popcll(__ballot(present != 0));
    int nfp    = __popcll(__ballot(fp != 0));
    #pragma unroll
    for (int o = 32; o >= 1; o >>= 1) dice += __shfl_xor(dice, o, 64);

    if (lane == 0) out[0] = (float)(dice / (double)(num_gt + nfp));
}

extern "C" void kernel_launch(void* const* d_in, const int* in_sizes, int n_in,
                              void* d_out, int out_size, void* d_ws, size_t ws_size,
                              hipStream_t stream) {
    const float* pred = (const float*)d_in[0];
    const int* gt = (const int*)d_in[1];
    float* out = (float*)d_out;
    unsigned* ws = (unsigned*)d_ws;
    const int n = in_sizes[0];

    hipMemsetAsync(ws, 0, WS_WORDS * sizeof(unsigned), stream);

    hist_kernel<<<GRID, BLOCK, 0, stream>>>(pred, gt, ws, n);
    finish_kernel<<<1, 64, 0, stream>>>(ws, out, n);
}